// Round 1
// baseline (279.743 us; speedup 1.0000x reference)
//
#include <hip/hip_runtime.h>

// ---------- types ----------
typedef __bf16 bf16x8 __attribute__((ext_vector_type(8)));
typedef float  f32x4  __attribute__((ext_vector_type(4)));

__device__ __forceinline__ unsigned short f2bf(float f) {
    union { float f; unsigned int u; } x; x.f = f;
    unsigned int r = (x.u + 0x7FFFu + ((x.u >> 16) & 1u)) >> 16;  // RNE
    return (unsigned short)r;
}

// ==========================================================================
// GEMM: C[m][n] = alpha * sum_k A[m][k]*B[k][n] (+bias[m]) (+resid)
// A stored [m][k] k-contiguous (row stride lda)
// B stored [n][k] k-contiguous (row stride ldb)
// TRANS_OUT: store C transposed as C[n][m] (row stride ldc)
// 128x128 tile, BK=32, 256 threads = 4 waves (2x2), wave tile 64x64 (4x4 MFMA)
// ==========================================================================
template<typename OutT, bool TRANS_OUT, bool HAS_BIAS, bool HAS_RESID>
__global__ __launch_bounds__(256) void gemm_k(
    const unsigned short* __restrict__ Ag, long sA, int lda,
    const unsigned short* __restrict__ Bg, long sB, int ldb,
    OutT* __restrict__ Cg, long sC, int ldc,
    const float* __restrict__ bias,
    const float* __restrict__ resid, long sR,
    float alpha, int K)
{
    __shared__ __align__(16) unsigned short As[128 * 40];  // pad 32->40: even bank spread
    __shared__ __align__(16) unsigned short Bs[128 * 40];

    const int tid  = threadIdx.x;
    const int lane = tid & 63;
    const int wave = tid >> 6;
    const int wm   = (wave >> 1) * 64;
    const int wn   = (wave & 1) * 64;
    const int l16  = lane & 15;
    const int quad = lane >> 4;

    const unsigned short* Ab = Ag + (long)blockIdx.z * sA + (long)(blockIdx.y * 128) * lda;
    const unsigned short* Bb = Bg + (long)blockIdx.z * sB + (long)(blockIdx.x * 128) * ldb;

    const int sm = tid >> 2;         // 0..63: row within half tile
    const int sk = (tid & 3) * 8;    // k offset (vec8)

    f32x4 acc[4][4] = {};

    for (int k0 = 0; k0 < K; k0 += 32) {
        uint4 a0 = *(const uint4*)(Ab + (long)sm * lda + k0 + sk);
        uint4 a1 = *(const uint4*)(Ab + (long)(sm + 64) * lda + k0 + sk);
        uint4 b0 = *(const uint4*)(Bb + (long)sm * ldb + k0 + sk);
        uint4 b1 = *(const uint4*)(Bb + (long)(sm + 64) * ldb + k0 + sk);
        __syncthreads();   // prior iter's frag reads done before overwrite
        *(uint4*)&As[sm * 40 + sk]        = a0;
        *(uint4*)&As[(sm + 64) * 40 + sk] = a1;
        *(uint4*)&Bs[sm * 40 + sk]        = b0;
        *(uint4*)&Bs[(sm + 64) * 40 + sk] = b1;
        __syncthreads();

        bf16x8 af[4], bfr[4];
        #pragma unroll
        for (int mi = 0; mi < 4; mi++)
            af[mi] = *(const bf16x8*)&As[(wm + mi * 16 + l16) * 40 + quad * 8];
        #pragma unroll
        for (int ni = 0; ni < 4; ni++)
            bfr[ni] = *(const bf16x8*)&Bs[(wn + ni * 16 + l16) * 40 + quad * 8];
        #pragma unroll
        for (int mi = 0; mi < 4; mi++)
            #pragma unroll
            for (int ni = 0; ni < 4; ni++)
                acc[mi][ni] = __builtin_amdgcn_mfma_f32_16x16x32_bf16(af[mi], bfr[ni], acc[mi][ni], 0, 0, 0);
    }

    // epilogue: D[m][n]: m = quad*4 + r, n = l16 per 16x16 tile
    const int mb = blockIdx.y * 128 + wm;
    const int nb = blockIdx.x * 128 + wn;
    #pragma unroll
    for (int mi = 0; mi < 4; mi++) {
        #pragma unroll
        for (int ni = 0; ni < 4; ni++) {
            f32x4 v = acc[mi][ni];
            const int m0 = mb + mi * 16 + quad * 4;
            const int n  = nb + ni * 16 + l16;
            float o[4];
            #pragma unroll
            for (int r = 0; r < 4; r++) {
                float val = v[r] * alpha;
                if (HAS_BIAS) val += bias[m0 + r];
                o[r] = val;
            }
            if constexpr (!TRANS_OUT) {
                const long base = (long)blockIdx.z * sC;
                #pragma unroll
                for (int r = 0; r < 4; r++) {
                    float val = o[r];
                    if (HAS_RESID) val += resid[(long)blockIdx.z * sR + (long)(m0 + r) * ldc + n];
                    long idx = base + (long)(m0 + r) * ldc + n;
                    if constexpr (sizeof(OutT) == 2) ((unsigned short*)Cg)[idx] = f2bf(val);
                    else                              ((float*)Cg)[idx] = val;
                }
            } else {
                const long idx = (long)blockIdx.z * sC + (long)n * ldc + m0;  // [n][m], 4 consecutive m
                if constexpr (sizeof(OutT) == 2) {
                    ushort4 p; p.x = f2bf(o[0]); p.y = f2bf(o[1]); p.z = f2bf(o[2]); p.w = f2bf(o[3]);
                    *(ushort4*)((unsigned short*)Cg + idx) = p;
                } else {
                    float4 p; p.x = o[0]; p.y = o[1]; p.z = o[2]; p.w = o[3];
                    *(float4*)((float*)Cg + idx) = p;
                }
            }
        }
    }
}

// ==========================================================================
// GroupNorm: x[b][c][n] (fp32) -> xnT[b][n][c] (bf16), 32 groups of 16 ch
// one block per (b, g): 16 ch x 1024 spatial = 16384 floats
// ==========================================================================
__global__ __launch_bounds__(256) void gn_k(
    const float* __restrict__ x, const float* __restrict__ gsc,
    const float* __restrict__ gbi, unsigned short* __restrict__ xnT)
{
    __shared__ __align__(16) unsigned short ln[16 * 1024];  // normalized bf16
    __shared__ float red[8];
    const int b = blockIdx.y, g = blockIdx.x;
    const int tid = threadIdx.x, lane = tid & 63, wv = tid >> 6;

    const float4* x4 = (const float4*)(x + ((long)b * 512 + g * 16) * 1024);
    float4 vals[16];
    float s = 0.f, ss = 0.f;
    #pragma unroll
    for (int i = 0; i < 16; i++) {
        float4 v = x4[tid + i * 256];
        vals[i] = v;
        s  += v.x + v.y + v.z + v.w;
        ss += v.x * v.x + v.y * v.y + v.z * v.z + v.w * v.w;
    }
    for (int o = 32; o; o >>= 1) { s += __shfl_down(s, o); ss += __shfl_down(ss, o); }
    if (lane == 0) { red[wv * 2] = s; red[wv * 2 + 1] = ss; }
    __syncthreads();
    const float S  = red[0] + red[2] + red[4] + red[6];
    const float SS = red[1] + red[3] + red[5] + red[7];
    const float mean = S * (1.f / 16384.f);
    const float var  = SS * (1.f / 16384.f) - mean * mean;
    const float inv  = rsqrtf(var + 1e-5f);

    #pragma unroll
    for (int i = 0; i < 16; i++) {
        const int idx = tid + i * 256;        // float4 units; 256 per channel
        const int c   = idx >> 8;
        const float sc = gsc[g * 16 + c] * inv;
        const float bi = gbi[g * 16 + c] - mean * sc;
        float4 v = vals[i];
        ushort4 p;
        p.x = f2bf(v.x * sc + bi); p.y = f2bf(v.y * sc + bi);
        p.z = f2bf(v.z * sc + bi); p.w = f2bf(v.w * sc + bi);
        ((ushort4*)ln)[idx] = p;
    }
    __syncthreads();

    // transposed write: xnT[b][n][g*16 + c], 16 c per n = 2x uint4
    unsigned short* op = xnT + (long)b * 1024 * 512 + g * 16;
    for (int rep = 0; rep < 4; rep++) {
        const int n = rep * 256 + tid;
        union { unsigned short u[16]; uint4 v[2]; } t;
        #pragma unroll
        for (int c = 0; c < 16; c++) t.u[c] = ln[c * 1024 + n];
        *(uint4*)&op[(long)n * 512]     = t.v[0];
        *(uint4*)&op[(long)n * 512 + 8] = t.v[1];
    }
}

// ==========================================================================
// Softmax over rows of S (fp32 [16][1024][1024]); writes bf16 A in place
// (bf16 row stride 2048 elements == same 4096-byte row starts)
// ==========================================================================
__global__ __launch_bounds__(256) void softmax_k(float* __restrict__ S)
{
    __shared__ float red[4];
    const long row = (long)blockIdx.y * 1024 + blockIdx.x;
    float* sp = S + row * 1024;
    const int tid = threadIdx.x, lane = tid & 63, wv = tid >> 6;

    float4 v = ((const float4*)sp)[tid];
    float mx = fmaxf(fmaxf(v.x, v.y), fmaxf(v.z, v.w));
    for (int o = 32; o; o >>= 1) mx = fmaxf(mx, __shfl_down(mx, o));
    if (lane == 0) red[wv] = mx;
    __syncthreads();
    mx = fmaxf(fmaxf(red[0], red[1]), fmaxf(red[2], red[3]));

    float e0 = __expf(v.x - mx), e1 = __expf(v.y - mx);
    float e2 = __expf(v.z - mx), e3 = __expf(v.w - mx);
    float sum = e0 + e1 + e2 + e3;
    for (int o = 32; o; o >>= 1) sum += __shfl_down(sum, o);
    __syncthreads();                 // everyone done reading red (and sp)
    if (lane == 0) red[wv] = sum;
    __syncthreads();
    const float inv = 1.f / (red[0] + red[1] + red[2] + red[3]);

    ushort4 o4;
    o4.x = f2bf(e0 * inv); o4.y = f2bf(e1 * inv);
    o4.z = f2bf(e2 * inv); o4.w = f2bf(e3 * inv);
    ((ushort4*)sp)[tid] = o4;        // in-place bf16
}

// ---------- weights fp32 -> bf16 (wq|wk|wv|wp concatenated) ----------
__global__ __launch_bounds__(256) void wconv_k(
    const float* __restrict__ w0, const float* __restrict__ w1,
    const float* __restrict__ w2, const float* __restrict__ w3,
    unsigned short* __restrict__ out)
{
    const int m = blockIdx.y;
    const float* src = (m == 0) ? w0 : (m == 1) ? w1 : (m == 2) ? w2 : w3;
    const int i = blockIdx.x * 256 + threadIdx.x;  // float4 units, 65536 per matrix
    float4 v = ((const float4*)src)[i];
    ushort4 o; o.x = f2bf(v.x); o.y = f2bf(v.y); o.z = f2bf(v.z); o.w = f2bf(v.w);
    ((ushort4*)(out + (long)m * 262144))[i] = o;
}

// ==========================================================================
extern "C" void kernel_launch(void* const* d_in, const int* in_sizes, int n_in,
                              void* d_out, int out_size, void* d_ws, size_t ws_size,
                              hipStream_t stream)
{
    const float* x   = (const float*)d_in[0];
    const float* gsc = (const float*)d_in[1];
    const float* gbi = (const float*)d_in[2];
    const float* wq  = (const float*)d_in[3];
    const float* bq  = (const float*)d_in[4];
    const float* wk  = (const float*)d_in[5];
    const float* bk  = (const float*)d_in[6];
    const float* wv  = (const float*)d_in[7];
    const float* bv  = (const float*)d_in[8];
    const float* wp  = (const float*)d_in[9];
    const float* bp  = (const float*)d_in[10];
    float* out = (float*)d_out;

    char* ws = (char*)d_ws;
    unsigned short* xnT = (unsigned short*)(ws);               // 16 MB [b][n][c], later reused as OT
    unsigned short* qT  = (unsigned short*)(ws + 16777216);    // 16 MB [b][i][c]
    unsigned short* kT  = (unsigned short*)(ws + 33554432);    // 16 MB [b][j][c]
    unsigned short* vB  = (unsigned short*)(ws + 50331648);    // 16 MB [b][c][j]
    float*          Sb  = (float*)        (ws + 67108864);     // 67 MB [b][i][j] (bf16 A aliased)
    unsigned short* Wb  = (unsigned short*)(ws + 134217728);   // 2 MB: wq|wk|wv|wp bf16
    unsigned short* OT  = xnT;                                 // alias: xnT dead after QKV

    const long sBCN = 512L * 1024;   // per-batch elements of [512][1024] / [1024][512]

    wconv_k<<<dim3(256, 4), 256, 0, stream>>>(wq, wk, wv, wp, Wb);
    gn_k<<<dim3(32, 16), 256, 0, stream>>>(x, gsc, gbi, xnT);

    // Q = Wq * xn  -> qT[i][d]   (transposed epilogue)
    gemm_k<unsigned short, true, true, false><<<dim3(8, 4, 16), 256, 0, stream>>>(
        Wb, 0, 512, xnT, sBCN, 512, qT, sBCN, 512, bq, nullptr, 0, 1.f, 512);
    // K = Wk * xn  -> kT[j][d]
    gemm_k<unsigned short, true, true, false><<<dim3(8, 4, 16), 256, 0, stream>>>(
        Wb + 262144, 0, 512, xnT, sBCN, 512, kT, sBCN, 512, bk, nullptr, 0, 1.f, 512);
    // V = Wv * xn  -> v[d][j]    (natural epilogue)
    gemm_k<unsigned short, false, true, false><<<dim3(8, 4, 16), 256, 0, stream>>>(
        Wb + 524288, 0, 512, xnT, sBCN, 512, vB, sBCN, 1024, bv, nullptr, 0, 1.f, 512);
    // S[i][j] = (1/sqrt(512)) * sum_c qT[i][c]*kT[j][c]   fp32
    gemm_k<float, false, false, false><<<dim3(8, 8, 16), 256, 0, stream>>>(
        qT, sBCN, 512, kT, sBCN, 512, Sb, 1048576L, 1024, nullptr, nullptr, 0,
        0.044194173824159216f, 512);
    softmax_k<<<dim3(1024, 16), 256, 0, stream>>>(Sb);
    // O[c][i] = sum_j v[c][j]*A[i][j] -> OT[i][c]  (A-op = v MK, B-op = A NK ldb=2048)
    gemm_k<unsigned short, true, false, false><<<dim3(8, 4, 16), 256, 0, stream>>>(
        vB, sBCN, 1024, (unsigned short*)Sb, 2097152L, 2048, OT, sBCN, 512,
        nullptr, nullptr, 0, 1.f, 1024);
    // out = Wp * O + bp + x   (fp32, natural epilogue, fused residual)
    gemm_k<float, false, true, true><<<dim3(8, 4, 16), 256, 0, stream>>>(
        Wb + 786432, 0, 512, OT, sBCN, 512, out, sBCN, 1024, bp, x, sBCN, 1.f, 512);
}